// Round 1
// baseline (96.394 us; speedup 1.0000x reference)
//
#include <hip/hip_runtime.h>

// DensityLoss: B=8, N=4096, radius=0.1, NSAMPLE=9, TOPK=5, H=0.12, EPS=1e-12
// Output: scalar mean over [B,N,TOPK-1] of (RADIUS - sqrt(ds)*exp(-ds/H^2))
//
// R6: grid-binned ball query. radius (0.1) == cell size of a 10^3 grid over
// [0,1]^3, so each query only needs its 27-cell neighborhood (~111 candidates
// avg) instead of the previous index-ordered scan of ~2700+ (and a full 4096
// scan for boundary points with <9 neighbors, which could never early-exit).
// Candidate-query pairs drop ~30x: 117M -> 3.6M.
//
// K1 (8 blocks x 1024): per-batch counting sort by cell. Records carry the
//   original point index so "first NSAMPLE by index" semantics survive.
// K2 (512 blocks x 64): one thread per query, queries walked in cell-sorted
//   order (lanes of a wave share nearly identical candidate ranges -> shared
//   L1/L2 lines, low divergence). 9-entry index-sorted insertion network in
//   registers (fully unrolled -> no scratch). Padding + top-5 epilogue carried
//   over unchanged from the verified R5 kernel.

#define NB 8
#define NPTS 4096
#define NS 9
#define RAD2 0.01f
#define H2 0.0144f
#define EPSV 1e-12f
#define SCALE (1.0f / 131072.0f)   // 1/(B*N*(TOPK-1)) = 1/(8*4096*4)
#define NCELL 1000
#define CS_STRIDE 1008
#define SENT 0x7fffffff

__device__ __forceinline__ int cell_coord(float v) {
    int c = (int)(v * 10.0f);
    return min(max(c, 0), 9);
}

// ---------------- K1: counting sort into 10x10x10 cells, one block/batch ----
__global__ __launch_bounds__(1024) void bin_kernel(
    const float* __restrict__ pred, float4* __restrict__ sorted,
    int* __restrict__ cellStart) {
    __shared__ int hist[NCELL];
    __shared__ int waveTot[16];
    const int tid  = threadIdx.x;
    const int lane = tid & 63;
    const int wid  = tid >> 6;
    const int b    = blockIdx.x;

    for (int i = tid; i < NCELL; i += 1024) hist[i] = 0;
    __syncthreads();

    // Thread t handles points 4t..4t+3: 3 coalesced float4 loads.
    const float* src = pred + (size_t)b * (NPTS * 3) + tid * 12;
    float4 a0 = *(const float4*)(src);
    float4 a1 = *(const float4*)(src + 4);
    float4 a2 = *(const float4*)(src + 8);
    float xs[4] = {a0.x, a0.w, a1.z, a2.y};
    float ys[4] = {a0.y, a1.x, a1.w, a2.z};
    float zs[4] = {a0.z, a1.y, a2.x, a2.w};
    int cell[4];
    #pragma unroll
    for (int k = 0; k < 4; ++k) {
        cell[k] = (cell_coord(xs[k]) * 10 + cell_coord(ys[k])) * 10 + cell_coord(zs[k]);
        atomicAdd(&hist[cell[k]], 1);
    }
    __syncthreads();

    // Block-wide exclusive scan over the 1000 counters.
    int v = (tid < NCELL) ? hist[tid] : 0;
    int incl = v;
    #pragma unroll
    for (int off = 1; off < 64; off <<= 1) {
        int n = __shfl_up(incl, off, 64);
        if (lane >= off) incl += n;
    }
    if (lane == 63) waveTot[wid] = incl;
    __syncthreads();
    if (tid == 0) {
        int run = 0;
        for (int w = 0; w < 16; ++w) { int t = waveTot[w]; waveTot[w] = run; run += t; }
    }
    __syncthreads();
    int excl = incl - v + waveTot[wid];
    if (tid < NCELL) cellStart[b * CS_STRIDE + tid] = excl;
    if (tid == 0)    cellStart[b * CS_STRIDE + NCELL] = NPTS;
    __syncthreads();
    if (tid < NCELL) hist[tid] = excl;   // reuse as scatter cursors
    __syncthreads();

    float4* dst = sorted + (size_t)b * NPTS;
    #pragma unroll
    for (int k = 0; k < 4; ++k) {
        int slot = atomicAdd(&hist[cell[k]], 1);
        dst[slot] = (float4){xs[k], ys[k], zs[k], __int_as_float(tid * 4 + k)};
    }
}

// ---------------- K2: one thread per query over 27-cell neighborhood --------
__global__ __launch_bounds__(64) void query_kernel(
    const float4* __restrict__ sorted, const int* __restrict__ cellStart,
    float* __restrict__ out) {
    __shared__ int cs[NCELL + 1];
    const int tid   = threadIdx.x;
    const int b     = blockIdx.x >> 6;
    const int jbase = (blockIdx.x & 63) << 6;   // 64 sorted queries per block

    const int* csg = cellStart + b * CS_STRIDE;
    for (int i = tid; i <= NCELL; i += 64) cs[i] = csg[i];
    __syncthreads();

    const float4* P = sorted + (size_t)b * NPTS;
    float4 me = P[jbase + tid];
    const float qx = me.x, qy = me.y, qz = me.z;
    const int cx = cell_coord(qx), cy = cell_coord(qy), cz = cell_coord(qz);

    // 9 smallest original indices among in-ball hits, with their distances.
    int   I[NS];
    float D[NS];
    #pragma unroll
    for (int t = 0; t < NS; ++t) { I[t] = SENT; D[t] = 0.0f; }

    const int x0 = max(cx - 1, 0), x1 = min(cx + 1, 9);
    const int y0 = max(cy - 1, 0), y1 = min(cy + 1, 9);
    const int z0 = max(cz - 1, 0), z1 = min(cz + 1, 9);

    for (int xx = x0; xx <= x1; ++xx) {
        for (int yy = y0; yy <= y1; ++yy) {
            const int base = (xx * 10 + yy) * 10;
            int s = cs[base + z0];
            int e = cs[base + z1 + 1];          // z cells are contiguous
            if (s >= e) continue;
            float4 c = P[s];
            for (int k = s; k < e; ++k) {
                int kn = (k + 1 < e) ? (k + 1) : k;   // 1-deep prefetch
                float4 cn = P[kn];
                float dx = c.x - qx, dy = c.y - qy, dz = c.z - qz;
                float d2 = dx * dx + dy * dy + dz * dz;  // same formula as R5
                int ci = __float_as_int(c.w);
                if (d2 <= RAD2 && ci < I[NS - 1]) {
                    int ii = ci; float dd = d2;
                    #pragma unroll
                    for (int t = 0; t < NS; ++t) {   // index-sorted insert
                        bool sw = ii < I[t];
                        int oI = I[t]; float oD = D[t];
                        I[t] = sw ? ii : oI;  D[t] = sw ? dd : oD;
                        ii   = sw ? oI : ii;  dd   = sw ? oD : dd;
                    }
                }
                c = cn;
            }
        }
    }

    // Pad missing slots with the first (smallest-index) hit's distance.
    // Self always hits (d2 = 0), so D[0] is valid.
    #pragma unroll
    for (int t = 1; t < NS; ++t) if (I[t] == SENT) D[t] = D[0];

    // Partial selection sort: 5 smallest ascending into D[0..4].
    #pragma unroll
    for (int i = 0; i < 5; ++i) {
        #pragma unroll
        for (int j = i + 1; j < NS; ++j) {
            float lo = fminf(D[i], D[j]);
            float hi = fmaxf(D[i], D[j]);
            D[i] = lo; D[j] = hi;
        }
    }
    float acc = 0.0f;
    #pragma unroll
    for (int i = 1; i < 5; ++i) {
        float cc = (D[i] < EPSV) ? EPSV : D[i];
        acc += 0.1f - sqrtf(cc) * expf(-cc / H2);
    }
    #pragma unroll
    for (int off = 32; off >= 1; off >>= 1)
        acc += __shfl_down(acc, off, 64);
    if (tid == 0) atomicAdd(out, acc * SCALE);
}

extern "C" void kernel_launch(void* const* d_in, const int* in_sizes, int n_in,
                              void* d_out, int out_size, void* d_ws, size_t ws_size,
                              hipStream_t stream) {
    const float* pred = (const float*)d_in[0];
    float* out = (float*)d_out;
    float4* sorted = (float4*)d_ws;
    int* cellStart = (int*)((char*)d_ws + (size_t)NB * NPTS * sizeof(float4));
    // d_out is re-poisoned to 0xAA before every timed launch — zero it ourselves.
    hipMemsetAsync(out, 0, sizeof(float), stream);
    bin_kernel<<<dim3(NB), dim3(1024), 0, stream>>>(pred, sorted, cellStart);
    query_kernel<<<dim3(NB * 64), dim3(64), 0, stream>>>(sorted, cellStart, out);
}